// Round 5
// baseline (397.210 us; speedup 1.0000x reference)
//
#include <hip/hip_runtime.h>

// SGConv: out = A_norm^2 (x @ W^T) + b, A_norm = D^-1/2 (A+I) D^-1/2.
// Linear first (128->64), then 2 hops in 64-dim with bf16 storage
// (fp32 accumulate) to halve the random gather traffic that bounds prop.

#define FIN 128
#define FOUT 64
#define BN 128
#define KC 64

typedef unsigned short ushort_t;
typedef unsigned int uint_t;

__device__ __forceinline__ ushort_t f2bf(float f) {           // RNE
    uint_t u = __float_as_uint(f);
    return (ushort_t)((u + 0x7fffu + ((u >> 16) & 1u)) >> 16);
}
__device__ __forceinline__ float bf2f(ushort_t v) {
    return __uint_as_float(((uint_t)v) << 16);
}

// ---- CSR build ------------------------------------------------------------

__global__ void count_kernel(const int* __restrict__ ei, int* __restrict__ cnt, int e) {
    int t = blockIdx.x * blockDim.x + threadIdx.x;
    if (t < e) atomicAdd(&cnt[ei[e + t]], 1);   // dst = ei[E + t]
}

__global__ void scan1_kernel(const int* __restrict__ cnt, int* __restrict__ excl,
                             int* __restrict__ bsum, int n) {
    __shared__ int tmp[256];
    int t = threadIdx.x;
    int idx = blockIdx.x * 256 + t;
    int v = (idx < n) ? cnt[idx] : 0;
    tmp[t] = v;
    __syncthreads();
    for (int off = 1; off < 256; off <<= 1) {
        int add = (t >= off) ? tmp[t - off] : 0;
        __syncthreads();
        tmp[t] += add;
        __syncthreads();
    }
    if (idx < n) excl[idx] = tmp[t] - v;
    if (t == 255) bsum[blockIdx.x] = tmp[255];
}

__global__ void scan2_kernel(int* __restrict__ bsum, int nb) {
    __shared__ int tmp[1024];
    int t = threadIdx.x;
    int v = (t < nb) ? bsum[t] : 0;
    tmp[t] = v;
    __syncthreads();
    for (int off = 1; off < 1024; off <<= 1) {
        int add = (t >= off) ? tmp[t - off] : 0;
        __syncthreads();
        tmp[t] += add;
        __syncthreads();
    }
    if (t < nb) bsum[t] = tmp[t] - v;
}

__global__ void scan3_kernel(const int* __restrict__ cnt, const int* __restrict__ excl,
                             const int* __restrict__ bsum, int* __restrict__ rowptr,
                             int* __restrict__ cursor, float* __restrict__ dinv,
                             int n, int e) {
    int idx = blockIdx.x * blockDim.x + threadIdx.x;
    if (idx < n) {
        int rp = excl[idx] + bsum[idx >> 8];
        rowptr[idx] = rp;
        cursor[idx] = rp;
        dinv[idx]   = rsqrtf((float)(cnt[idx] + 1));
    }
    if (idx == 0) rowptr[n] = e;
}

// scatter: claim slot via cursor atomic, store {src, dinv[s]*dinv[d]} packed
// in a long long via one 8B NT store (random 4B stores caused 102 MB of
// line writebacks in R2; builtin rejects HIP int2, so pack manually).
__global__ void scatter_kernel(const int* __restrict__ ei, int* __restrict__ cursor,
                               const float* __restrict__ dinv,
                               long long* __restrict__ cw, int e) {
    int t = blockIdx.x * blockDim.x + threadIdx.x;
    if (t < e) {
        int d = ei[e + t];
        int s = ei[t];
        int p = atomicAdd(&cursor[d], 1);
        unsigned long long v = (unsigned long long)(unsigned int)s |
            ((unsigned long long)(unsigned int)__float_as_int(dinv[s] * dinv[d]) << 32);
        __builtin_nontemporal_store((long long)v, &cw[p]);
    }
}

// ---- y0 = x @ W^T : register-tiled SGEMM, bf16 output ---------------------

__global__ __launch_bounds__(256) void xw_kernel(const float* __restrict__ x,
                                                 const float* __restrict__ W,
                                                 ushort_t* __restrict__ y, int n) {
    __shared__ float4 xs4[KC][33];
    __shared__ float4 ws4[KC][17];
    float* xsf = (float*)xs4;
    float* wsf = (float*)ws4;

    const int tid   = threadIdx.x;
    const int node0 = blockIdx.x * BN;
    const int n8 = tid >> 4;
    const int o4 = tid & 15;

    float4 acc[8];
#pragma unroll
    for (int i = 0; i < 8; ++i) acc[i] = make_float4(0.f, 0.f, 0.f, 0.f);

    const int rx = tid >> 4;
    const int cx = tid & 15;

    for (int p = 0; p < FIN / KC; ++p) {
        __syncthreads();
#pragma unroll
        for (int i = 0; i < 8; ++i) {
            int r  = rx + 16 * i;
            int nd = node0 + r; if (nd > n - 1) nd = n - 1;
            float4 v = *(const float4*)(x + (size_t)nd * FIN + p * KC + 4 * cx);
            float* dst = xsf + (4 * cx) * 132 + r;
            dst[0] = v.x; dst[132] = v.y; dst[264] = v.z; dst[396] = v.w;
        }
#pragma unroll
        for (int i = 0; i < 4; ++i) {
            int o = rx + 16 * i;
            float4 v = *(const float4*)(W + (size_t)o * FIN + p * KC + 4 * cx);
            float* dst = wsf + (4 * cx) * 68 + o;
            dst[0] = v.x; dst[68] = v.y; dst[136] = v.z; dst[204] = v.w;
        }
        __syncthreads();
#pragma unroll 4
        for (int k = 0; k < KC; ++k) {
            float4 xa0 = xs4[k][2 * n8];
            float4 xa1 = xs4[k][2 * n8 + 1];
            float4 wb  = ws4[k][o4];
            float xe[8] = {xa0.x, xa0.y, xa0.z, xa0.w, xa1.x, xa1.y, xa1.z, xa1.w};
#pragma unroll
            for (int i = 0; i < 8; ++i) {
                acc[i].x += xe[i] * wb.x;
                acc[i].y += xe[i] * wb.y;
                acc[i].z += xe[i] * wb.z;
                acc[i].w += xe[i] * wb.w;
            }
        }
    }
#pragma unroll
    for (int i = 0; i < 8; ++i) {
        int nd = node0 + 8 * n8 + i;
        if (nd < n) {
            ushort4 o;
            o.x = f2bf(acc[i].x); o.y = f2bf(acc[i].y);
            o.z = f2bf(acc[i].z); o.w = f2bf(acc[i].w);
            *(ushort4*)(y + (size_t)nd * FOUT + 4 * o4) = o;
        }
    }
}

// ---- one propagation hop (bf16 in; bf16 or fp32+bias out) -----------------
// Wave per node, lane = feature. wid forced wave-uniform (readfirstlane) so
// rowptr/cw loads become scalar; per-edge weight pre-fused -> the only
// vector memory op per edge is the 128B row gather.

__global__ void prop_kernel(const ushort_t* __restrict__ yin, const int* __restrict__ rowptr,
                            const long long* __restrict__ cw, const float* __restrict__ dinv,
                            const float* __restrict__ bias, ushort_t* __restrict__ yout_bf,
                            float* __restrict__ yout_f, int n, int mode) {
    int wid  = __builtin_amdgcn_readfirstlane((blockIdx.x * blockDim.x + threadIdx.x) >> 6);
    int lane = threadIdx.x & 63;
    if (wid >= n) return;
    float di  = dinv[wid];
    float acc = di * di * bf2f(yin[(size_t)wid * FOUT + lane]);
    int j = rowptr[wid], end = rowptr[wid + 1];
    for (; j + 3 < end; j += 4) {
        long long a0 = cw[j], a1 = cw[j + 1], a2 = cw[j + 2], a3 = cw[j + 3];
        int s0 = (int)(a0 & 0xffffffffLL), s1 = (int)(a1 & 0xffffffffLL);
        int s2 = (int)(a2 & 0xffffffffLL), s3 = (int)(a3 & 0xffffffffLL);
        float v0 = bf2f(yin[(size_t)s0 * FOUT + lane]);
        float v1 = bf2f(yin[(size_t)s1 * FOUT + lane]);
        float v2 = bf2f(yin[(size_t)s2 * FOUT + lane]);
        float v3 = bf2f(yin[(size_t)s3 * FOUT + lane]);
        acc += __int_as_float((int)(a0 >> 32)) * v0;
        acc += __int_as_float((int)(a1 >> 32)) * v1;
        acc += __int_as_float((int)(a2 >> 32)) * v2;
        acc += __int_as_float((int)(a3 >> 32)) * v3;
    }
    for (; j < end; ++j) {
        long long a = cw[j];
        int s = (int)(a & 0xffffffffLL);
        acc += __int_as_float((int)(a >> 32)) * bf2f(yin[(size_t)s * FOUT + lane]);
    }
    if (mode == 0) {
        yout_bf[(size_t)wid * FOUT + lane] = f2bf(acc);
    } else {
        yout_f[(size_t)wid * FOUT + lane] = acc + bias[lane];
    }
}

// ---- launch ---------------------------------------------------------------

extern "C" void kernel_launch(void* const* d_in, const int* in_sizes, int n_in,
                              void* d_out, int out_size, void* d_ws, size_t ws_size,
                              hipStream_t stream) {
    const float* x  = (const float*)d_in[0];
    const int*   ei = (const int*)d_in[1];
    const float* W  = (const float*)d_in[2];
    const float* b  = (const float*)d_in[3];
    float* out = (float*)d_out;

    int n = in_sizes[0] / FIN;   // 100000
    int e = in_sizes[1] / 2;     // 1600000
    int NB = (n + 255) / 256;    // 391 (<= 1024 required by scan2)

    char* w = (char*)d_ws;
    long long* cw  = (long long*)w; w += (size_t)e * sizeof(long long);  // 8B-aligned first
    ushort_t* y0b  = (ushort_t*)w;  w += (size_t)n * FOUT * sizeof(ushort_t);
    ushort_t* y1b  = (ushort_t*)w;  w += (size_t)n * FOUT * sizeof(ushort_t);
    int*   cnt    = (int*)w;   w += (size_t)n * sizeof(int);
    int*   rowptr = (int*)w;   w += (size_t)(n + 1) * sizeof(int);
    int*   cursor = (int*)w;   w += (size_t)n * sizeof(int);
    int*   excl   = (int*)w;   w += (size_t)n * sizeof(int);
    int*   bsum   = (int*)w;   w += (size_t)NB * sizeof(int);
    float* dinv   = (float*)w; w += (size_t)n * sizeof(float);

    int eb = (e + 255) / 256;

    (void)hipMemsetAsync(cnt, 0, (size_t)n * sizeof(int), stream);
    count_kernel<<<eb, 256, 0, stream>>>(ei, cnt, e);
    scan1_kernel<<<NB, 256, 0, stream>>>(cnt, excl, bsum, n);
    scan2_kernel<<<1, 1024, 0, stream>>>(bsum, NB);
    scan3_kernel<<<NB, 256, 0, stream>>>(cnt, excl, bsum, rowptr, cursor, dinv, n, e);
    scatter_kernel<<<eb, 256, 0, stream>>>(ei, cursor, dinv, cw, e);

    xw_kernel<<<(n + BN - 1) / BN, 256, 0, stream>>>(x, W, y0b, n);
    prop_kernel<<<(n + 3) / 4, 256, 0, stream>>>(y0b, rowptr, cw, dinv, nullptr, y1b, nullptr, n, 0);
    prop_kernel<<<(n + 3) / 4, 256, 0, stream>>>(y1b, rowptr, cw, dinv, b, nullptr, out, n, 1);
}

// Round 6
// 333.116 us; speedup vs baseline: 1.1924x; 1.1924x over previous
//
#include <hip/hip_runtime.h>

// SGConv: out = A_norm^2 (x @ W^T) + b, A_norm = D^-1/2 (A+I) D^-1/2.
// Linear first (128->64), then 2 hops in 64-dim, bf16 storage / fp32 accum.
// CSR build is a bucketed counting sort so ALL scatter writes are dense
// (R5 profile: random 8B NT scatter cost 102 MB of full-line writebacks).

#define FIN 128
#define FOUT 64
#define BN 128
#define KC 64

#define BSH 7            // 128 nodes per bucket
#define NGRP 8           // segment groups (~XCD affinity via blockIdx%8)
#define CAP 512          // per-(bucket,group) capacity; mean 256, std 16

typedef unsigned short ushort_t;
typedef unsigned int uint_t;

__device__ __forceinline__ ushort_t f2bf(float f) {           // RNE
    uint_t u = __float_as_uint(f);
    return (ushort_t)((u + 0x7fffu + ((u >> 16) & 1u)) >> 16);
}
__device__ __forceinline__ float bf2f(ushort_t v) {
    return __uint_as_float(((uint_t)v) << 16);
}

// ---- CSR build: bucketed counting sort ------------------------------------

// p1: append packed {dst_low7, src} into per-(bucket, blockIdx%8) segment.
// Plain stores (NOT nontemporal): appends are sequential per segment, lines
// fill inside one XCD's L2 -> dense writeback.
__global__ void p1_bucket_kernel(const int* __restrict__ ei, int* __restrict__ bcur,
                                 int* __restrict__ bbuf, int e) {
    int t = blockIdx.x * blockDim.x + threadIdx.x;
    if (t < e) {
        int s = ei[t];
        int d = ei[e + t];
        int seg = ((d >> BSH) << 3) | (blockIdx.x & (NGRP - 1));
        int pos = atomicAdd(&bcur[seg], 1);
        if (pos < CAP)
            bbuf[(seg << 9) + pos] = ((d & 127) << 17) | s;   // src < 2^17
    }
}

// p2a: per-bucket histogram in LDS -> coalesced cnt write (replaces the
// global-atomic count kernel).
__global__ void p2a_count_kernel(const int* __restrict__ bcur, const int* __restrict__ bbuf,
                                 int* __restrict__ cnt, int n) {
    __shared__ int lc[128];
    int b = blockIdx.x, tid = threadIdx.x;
    if (tid < 128) lc[tid] = 0;
    __syncthreads();
    for (int g = 0; g < NGRP; ++g) {
        int seg = (b << 3) | g;
        int m = bcur[seg]; if (m > CAP) m = CAP;
        const int* p = bbuf + (seg << 9);
        for (int i = tid; i < m; i += 256)
            atomicAdd(&lc[(p[i] >> 17) & 127], 1);
    }
    __syncthreads();
    int node = (b << BSH) + tid;
    if (tid < 128 && node < n) cnt[node] = lc[tid];
}

__global__ void scan1_kernel(const int* __restrict__ cnt, int* __restrict__ excl,
                             int* __restrict__ bsum, int n) {
    __shared__ int tmp[256];
    int t = threadIdx.x;
    int idx = blockIdx.x * 256 + t;
    int v = (idx < n) ? cnt[idx] : 0;
    tmp[t] = v;
    __syncthreads();
    for (int off = 1; off < 256; off <<= 1) {
        int add = (t >= off) ? tmp[t - off] : 0;
        __syncthreads();
        tmp[t] += add;
        __syncthreads();
    }
    if (idx < n) excl[idx] = tmp[t] - v;
    if (t == 255) bsum[blockIdx.x] = tmp[255];
}

__global__ void scan2_kernel(int* __restrict__ bsum, int nb) {
    __shared__ int tmp[1024];
    int t = threadIdx.x;
    int v = (t < nb) ? bsum[t] : 0;
    tmp[t] = v;
    __syncthreads();
    for (int off = 1; off < 1024; off <<= 1) {
        int add = (t >= off) ? tmp[t - off] : 0;
        __syncthreads();
        tmp[t] += add;
        __syncthreads();
    }
    if (t < nb) bsum[t] = tmp[t] - v;
}

__global__ void scan3_kernel(const int* __restrict__ cnt, const int* __restrict__ excl,
                             const int* __restrict__ bsum, int* __restrict__ rowptr,
                             float* __restrict__ dinv, int n, int e) {
    int idx = blockIdx.x * blockDim.x + threadIdx.x;
    if (idx < n) {
        rowptr[idx] = excl[idx] + bsum[idx >> 8];
        dinv[idx]   = rsqrtf((float)(cnt[idx] + 1));
    }
    if (idx == 0) rowptr[n] = e;
}

// p2b: per-bucket placement. LDS cursors seeded from rowptr; each block
// writes a contiguous ~16KB output window -> dense, single-XCD writeback.
__global__ void p2b_place_kernel(const int* __restrict__ bcur, const int* __restrict__ bbuf,
                                 const int* __restrict__ rowptr, const float* __restrict__ dinv,
                                 long long* __restrict__ cw, int n) {
    __shared__ int lcur[128];
    __shared__ float ldin[128];
    int b = blockIdx.x, tid = threadIdx.x;
    if (tid < 128) {
        int node = (b << BSH) + tid;
        lcur[tid] = (node < n) ? rowptr[node] : 0;
        ldin[tid] = (node < n) ? dinv[node] : 0.f;
    }
    __syncthreads();
    for (int g = 0; g < NGRP; ++g) {
        int seg = (b << 3) | g;
        int m = bcur[seg]; if (m > CAP) m = CAP;
        const int* p = bbuf + (seg << 9);
        for (int i = tid; i < m; i += 256) {
            int v  = p[i];
            int s  = v & 0x1FFFF;
            int dl = (v >> 17) & 127;
            int pos = atomicAdd(&lcur[dl], 1);
            float w = dinv[s] * ldin[dl];
            unsigned long long pk = (unsigned long long)(unsigned int)s |
                ((unsigned long long)(unsigned int)__float_as_int(w) << 32);
            cw[pos] = (long long)pk;
        }
    }
}

// ---- y0 = x @ W^T : register-tiled SGEMM, bf16 output ---------------------

__global__ __launch_bounds__(256) void xw_kernel(const float* __restrict__ x,
                                                 const float* __restrict__ W,
                                                 ushort_t* __restrict__ y, int n) {
    __shared__ float4 xs4[KC][33];
    __shared__ float4 ws4[KC][17];
    float* xsf = (float*)xs4;
    float* wsf = (float*)ws4;

    const int tid   = threadIdx.x;
    const int node0 = blockIdx.x * BN;
    const int n8 = tid >> 4;
    const int o4 = tid & 15;

    float4 acc[8];
#pragma unroll
    for (int i = 0; i < 8; ++i) acc[i] = make_float4(0.f, 0.f, 0.f, 0.f);

    const int rx = tid >> 4;
    const int cx = tid & 15;

    for (int p = 0; p < FIN / KC; ++p) {
        __syncthreads();
#pragma unroll
        for (int i = 0; i < 8; ++i) {
            int r  = rx + 16 * i;
            int nd = node0 + r; if (nd > n - 1) nd = n - 1;
            float4 v = *(const float4*)(x + (size_t)nd * FIN + p * KC + 4 * cx);
            float* dst = xsf + (4 * cx) * 132 + r;
            dst[0] = v.x; dst[132] = v.y; dst[264] = v.z; dst[396] = v.w;
        }
#pragma unroll
        for (int i = 0; i < 4; ++i) {
            int o = rx + 16 * i;
            float4 v = *(const float4*)(W + (size_t)o * FIN + p * KC + 4 * cx);
            float* dst = wsf + (4 * cx) * 68 + o;
            dst[0] = v.x; dst[68] = v.y; dst[136] = v.z; dst[204] = v.w;
        }
        __syncthreads();
#pragma unroll 4
        for (int k = 0; k < KC; ++k) {
            float4 xa0 = xs4[k][2 * n8];
            float4 xa1 = xs4[k][2 * n8 + 1];
            float4 wb  = ws4[k][o4];
            float xe[8] = {xa0.x, xa0.y, xa0.z, xa0.w, xa1.x, xa1.y, xa1.z, xa1.w};
#pragma unroll
            for (int i = 0; i < 8; ++i) {
                acc[i].x += xe[i] * wb.x;
                acc[i].y += xe[i] * wb.y;
                acc[i].z += xe[i] * wb.z;
                acc[i].w += xe[i] * wb.w;
            }
        }
    }
#pragma unroll
    for (int i = 0; i < 8; ++i) {
        int nd = node0 + 8 * n8 + i;
        if (nd < n) {
            ushort4 o;
            o.x = f2bf(acc[i].x); o.y = f2bf(acc[i].y);
            o.z = f2bf(acc[i].z); o.w = f2bf(acc[i].w);
            *(ushort4*)(y + (size_t)nd * FOUT + 4 * o4) = o;
        }
    }
}

// ---- one propagation hop (bf16 in; bf16 or fp32+bias out) -----------------

__global__ void prop_kernel(const ushort_t* __restrict__ yin, const int* __restrict__ rowptr,
                            const long long* __restrict__ cw, const float* __restrict__ dinv,
                            const float* __restrict__ bias, ushort_t* __restrict__ yout_bf,
                            float* __restrict__ yout_f, int n, int mode) {
    int wid  = __builtin_amdgcn_readfirstlane((blockIdx.x * blockDim.x + threadIdx.x) >> 6);
    int lane = threadIdx.x & 63;
    if (wid >= n) return;
    float di  = dinv[wid];
    float acc = di * di * bf2f(yin[(size_t)wid * FOUT + lane]);
    int j = rowptr[wid], end = rowptr[wid + 1];
    for (; j + 3 < end; j += 4) {
        long long a0 = cw[j], a1 = cw[j + 1], a2 = cw[j + 2], a3 = cw[j + 3];
        int s0 = (int)(a0 & 0xffffffffLL), s1 = (int)(a1 & 0xffffffffLL);
        int s2 = (int)(a2 & 0xffffffffLL), s3 = (int)(a3 & 0xffffffffLL);
        float v0 = bf2f(yin[(size_t)s0 * FOUT + lane]);
        float v1 = bf2f(yin[(size_t)s1 * FOUT + lane]);
        float v2 = bf2f(yin[(size_t)s2 * FOUT + lane]);
        float v3 = bf2f(yin[(size_t)s3 * FOUT + lane]);
        acc += __int_as_float((int)(a0 >> 32)) * v0;
        acc += __int_as_float((int)(a1 >> 32)) * v1;
        acc += __int_as_float((int)(a2 >> 32)) * v2;
        acc += __int_as_float((int)(a3 >> 32)) * v3;
    }
    for (; j < end; ++j) {
        long long a = cw[j];
        int s = (int)(a & 0xffffffffLL);
        acc += __int_as_float((int)(a >> 32)) * bf2f(yin[(size_t)s * FOUT + lane]);
    }
    if (mode == 0) {
        yout_bf[(size_t)wid * FOUT + lane] = f2bf(acc);
    } else {
        yout_f[(size_t)wid * FOUT + lane] = acc + bias[lane];
    }
}

// ---- launch ---------------------------------------------------------------

extern "C" void kernel_launch(void* const* d_in, const int* in_sizes, int n_in,
                              void* d_out, int out_size, void* d_ws, size_t ws_size,
                              hipStream_t stream) {
    const float* x  = (const float*)d_in[0];
    const int*   ei = (const int*)d_in[1];
    const float* W  = (const float*)d_in[2];
    const float* b  = (const float*)d_in[3];
    float* out = (float*)d_out;

    int n = in_sizes[0] / FIN;   // 100000
    int e = in_sizes[1] / 2;     // 1600000
    int NB   = (n + 255) / 256;          // 391 (<= 1024 for scan2)
    int NBUK = (n + 127) >> BSH;         // 782 buckets

    char* w = (char*)d_ws;
    long long* cw  = (long long*)w; w += (size_t)e * sizeof(long long);      // 12.8 MB
    int*   bbuf   = (int*)w;   w += (size_t)NBUK * NGRP * CAP * sizeof(int); // 12.8 MB
    ushort_t* y0b = (ushort_t*)w; w += (size_t)n * FOUT * sizeof(ushort_t);  // 12.8 MB
    ushort_t* y1b = (ushort_t*)w; w += (size_t)n * FOUT * sizeof(ushort_t);  // 12.8 MB
    int*   bcur   = (int*)w;   w += (size_t)NBUK * NGRP * sizeof(int);
    int*   cnt    = (int*)w;   w += (size_t)n * sizeof(int);
    int*   rowptr = (int*)w;   w += (size_t)(n + 1) * sizeof(int);
    int*   excl   = (int*)w;   w += (size_t)n * sizeof(int);
    int*   bsum   = (int*)w;   w += (size_t)NB * sizeof(int);
    float* dinv   = (float*)w; w += (size_t)n * sizeof(float);

    int eb = (e + 255) / 256;

    (void)hipMemsetAsync(bcur, 0, (size_t)NBUK * NGRP * sizeof(int), stream);
    p1_bucket_kernel<<<eb, 256, 0, stream>>>(ei, bcur, bbuf, e);
    p2a_count_kernel<<<NBUK, 256, 0, stream>>>(bcur, bbuf, cnt, n);
    scan1_kernel<<<NB, 256, 0, stream>>>(cnt, excl, bsum, n);
    scan2_kernel<<<1, 1024, 0, stream>>>(bsum, NB);
    scan3_kernel<<<NB, 256, 0, stream>>>(cnt, excl, bsum, rowptr, dinv, n, e);
    p2b_place_kernel<<<NBUK, 256, 0, stream>>>(bcur, bbuf, rowptr, dinv, cw, n);

    xw_kernel<<<(n + BN - 1) / BN, 256, 0, stream>>>(x, W, y0b, n);
    prop_kernel<<<(n + 3) / 4, 256, 0, stream>>>(y0b, rowptr, cw, dinv, nullptr, y1b, nullptr, n, 0);
    prop_kernel<<<(n + 3) / 4, 256, 0, stream>>>(y1b, rowptr, cw, dinv, b, nullptr, out, n, 1);
}

// Round 7
// 332.830 us; speedup vs baseline: 1.1934x; 1.0009x over previous
//
#include <hip/hip_runtime.h>

// SGConv: out = A_norm^2 (x @ W^T) + b, A_norm = D^-1/2 (A+I) D^-1/2.
// Linear first (128->64), then 2 hops in 64-dim, bf16 storage / fp32 accum.
// CSR build is a bucketed counting sort; p1 groups segment appends by the
// REAL XCD id (HW_REG_XCC_ID) so each 64B line fills inside one L2 before
// writeback (R6: blockIdx%8 grouping gave 4.5 partial writebacks/line).

#define FIN 128
#define FOUT 64
#define BN 128
#define KC 64

#define BSH 7            // 128 nodes per bucket
#define NGRP 8           // segment groups = XCDs
#define CAP 512          // per-(bucket,group) capacity; mean 256, std 16

typedef unsigned short ushort_t;
typedef unsigned int uint_t;

__device__ __forceinline__ ushort_t f2bf(float f) {           // RNE
    uint_t u = __float_as_uint(f);
    return (ushort_t)((u + 0x7fffu + ((u >> 16) & 1u)) >> 16);
}
__device__ __forceinline__ float bf2f(ushort_t v) {
    return __uint_as_float(((uint_t)v) << 16);
}

__device__ __forceinline__ int xcc_id() {
    int x;
    asm volatile("s_getreg_b32 %0, hwreg(HW_REG_XCC_ID)" : "=s"(x));
    return x & (NGRP - 1);
}

// ---- CSR build: bucketed counting sort ------------------------------------

// p1: append packed {dst_low7, src} into per-(bucket, xcc) segment.
__global__ void p1_bucket_kernel(const int* __restrict__ ei, int* __restrict__ bcur,
                                 int* __restrict__ bbuf, int e) {
    int t = blockIdx.x * blockDim.x + threadIdx.x;
    int g = xcc_id();
    if (t < e) {
        int s = ei[t];
        int d = ei[e + t];
        int seg = ((d >> BSH) << 3) | g;
        int pos = atomicAdd(&bcur[seg], 1);
        if (pos < CAP)
            bbuf[(seg << 9) + pos] = ((d & 127) << 17) | s;   // src < 2^17
    }
}

// p2a: per-bucket histogram in LDS -> coalesced cnt write.
__global__ void p2a_count_kernel(const int* __restrict__ bcur, const int* __restrict__ bbuf,
                                 int* __restrict__ cnt, int n) {
    __shared__ int lc[128];
    int b = blockIdx.x, tid = threadIdx.x;
    if (tid < 128) lc[tid] = 0;
    __syncthreads();
    for (int g = 0; g < NGRP; ++g) {
        int seg = (b << 3) | g;
        int m = bcur[seg]; if (m > CAP) m = CAP;
        const int* p = bbuf + (seg << 9);
        for (int i = tid; i < m; i += 256)
            atomicAdd(&lc[(p[i] >> 17) & 127], 1);
    }
    __syncthreads();
    int node = (b << BSH) + tid;
    if (tid < 128 && node < n) cnt[node] = lc[tid];
}

__global__ void scan1_kernel(const int* __restrict__ cnt, int* __restrict__ excl,
                             int* __restrict__ bsum, int n) {
    __shared__ int tmp[256];
    int t = threadIdx.x;
    int idx = blockIdx.x * 256 + t;
    int v = (idx < n) ? cnt[idx] : 0;
    tmp[t] = v;
    __syncthreads();
    for (int off = 1; off < 256; off <<= 1) {
        int add = (t >= off) ? tmp[t - off] : 0;
        __syncthreads();
        tmp[t] += add;
        __syncthreads();
    }
    if (idx < n) excl[idx] = tmp[t] - v;
    if (t == 255) bsum[blockIdx.x] = tmp[255];
}

__global__ void scan2_kernel(int* __restrict__ bsum, int nb) {
    __shared__ int tmp[1024];
    int t = threadIdx.x;
    int v = (t < nb) ? bsum[t] : 0;
    tmp[t] = v;
    __syncthreads();
    for (int off = 1; off < 1024; off <<= 1) {
        int add = (t >= off) ? tmp[t - off] : 0;
        __syncthreads();
        tmp[t] += add;
        __syncthreads();
    }
    if (t < nb) bsum[t] = tmp[t] - v;
}

__global__ void scan3_kernel(const int* __restrict__ cnt, const int* __restrict__ excl,
                             const int* __restrict__ bsum, int* __restrict__ rowptr,
                             float* __restrict__ dinv, int n, int e) {
    int idx = blockIdx.x * blockDim.x + threadIdx.x;
    if (idx < n) {
        rowptr[idx] = excl[idx] + bsum[idx >> 8];
        dinv[idx]   = rsqrtf((float)(cnt[idx] + 1));
    }
    if (idx == 0) rowptr[n] = e;
}

// p2b: per-bucket placement into a contiguous ~16KB output window.
__global__ void p2b_place_kernel(const int* __restrict__ bcur, const int* __restrict__ bbuf,
                                 const int* __restrict__ rowptr, const float* __restrict__ dinv,
                                 long long* __restrict__ cw, int n) {
    __shared__ int lcur[128];
    __shared__ float ldin[128];
    int b = blockIdx.x, tid = threadIdx.x;
    if (tid < 128) {
        int node = (b << BSH) + tid;
        lcur[tid] = (node < n) ? rowptr[node] : 0;
        ldin[tid] = (node < n) ? dinv[node] : 0.f;
    }
    __syncthreads();
    for (int g = 0; g < NGRP; ++g) {
        int seg = (b << 3) | g;
        int m = bcur[seg]; if (m > CAP) m = CAP;
        const int* p = bbuf + (seg << 9);
        for (int i = tid; i < m; i += 256) {
            int v  = p[i];
            int s  = v & 0x1FFFF;
            int dl = (v >> 17) & 127;
            int pos = atomicAdd(&lcur[dl], 1);
            float w = dinv[s] * ldin[dl];
            unsigned long long pk = (unsigned long long)(unsigned int)s |
                ((unsigned long long)(unsigned int)__float_as_int(w) << 32);
            cw[pos] = (long long)pk;
        }
    }
}

// ---- y0 = x @ W^T : register-tiled SGEMM, bf16 output ---------------------

__global__ __launch_bounds__(256) void xw_kernel(const float* __restrict__ x,
                                                 const float* __restrict__ W,
                                                 ushort_t* __restrict__ y, int n) {
    __shared__ float4 xs4[KC][33];
    __shared__ float4 ws4[KC][17];
    float* xsf = (float*)xs4;
    float* wsf = (float*)ws4;

    const int tid   = threadIdx.x;
    const int node0 = blockIdx.x * BN;
    const int n8 = tid >> 4;
    const int o4 = tid & 15;

    float4 acc[8];
#pragma unroll
    for (int i = 0; i < 8; ++i) acc[i] = make_float4(0.f, 0.f, 0.f, 0.f);

    const int rx = tid >> 4;
    const int cx = tid & 15;

    for (int p = 0; p < FIN / KC; ++p) {
        __syncthreads();
#pragma unroll
        for (int i = 0; i < 8; ++i) {
            int r  = rx + 16 * i;
            int nd = node0 + r; if (nd > n - 1) nd = n - 1;
            float4 v = *(const float4*)(x + (size_t)nd * FIN + p * KC + 4 * cx);
            float* dst = xsf + (4 * cx) * 132 + r;
            dst[0] = v.x; dst[132] = v.y; dst[264] = v.z; dst[396] = v.w;
        }
#pragma unroll
        for (int i = 0; i < 4; ++i) {
            int o = rx + 16 * i;
            float4 v = *(const float4*)(W + (size_t)o * FIN + p * KC + 4 * cx);
            float* dst = wsf + (4 * cx) * 68 + o;
            dst[0] = v.x; dst[68] = v.y; dst[136] = v.z; dst[204] = v.w;
        }
        __syncthreads();
#pragma unroll 4
        for (int k = 0; k < KC; ++k) {
            float4 xa0 = xs4[k][2 * n8];
            float4 xa1 = xs4[k][2 * n8 + 1];
            float4 wb  = ws4[k][o4];
            float xe[8] = {xa0.x, xa0.y, xa0.z, xa0.w, xa1.x, xa1.y, xa1.z, xa1.w};
#pragma unroll
            for (int i = 0; i < 8; ++i) {
                acc[i].x += xe[i] * wb.x;
                acc[i].y += xe[i] * wb.y;
                acc[i].z += xe[i] * wb.z;
                acc[i].w += xe[i] * wb.w;
            }
        }
    }
#pragma unroll
    for (int i = 0; i < 8; ++i) {
        int nd = node0 + 8 * n8 + i;
        if (nd < n) {
            ushort4 o;
            o.x = f2bf(acc[i].x); o.y = f2bf(acc[i].y);
            o.z = f2bf(acc[i].z); o.w = f2bf(acc[i].w);
            *(ushort4*)(y + (size_t)nd * FOUT + 4 * o4) = o;
        }
    }
}

// ---- one propagation hop (bf16 in; bf16 or fp32+bias out) -----------------

__global__ void prop_kernel(const ushort_t* __restrict__ yin, const int* __restrict__ rowptr,
                            const long long* __restrict__ cw, const float* __restrict__ dinv,
                            const float* __restrict__ bias, ushort_t* __restrict__ yout_bf,
                            float* __restrict__ yout_f, int n, int mode) {
    int wid  = __builtin_amdgcn_readfirstlane((blockIdx.x * blockDim.x + threadIdx.x) >> 6);
    int lane = threadIdx.x & 63;
    if (wid >= n) return;
    float di  = dinv[wid];
    float acc = di * di * bf2f(yin[(size_t)wid * FOUT + lane]);
    int j = rowptr[wid], end = rowptr[wid + 1];
    for (; j + 3 < end; j += 4) {
        long long a0 = cw[j], a1 = cw[j + 1], a2 = cw[j + 2], a3 = cw[j + 3];
        int s0 = (int)(a0 & 0xffffffffLL), s1 = (int)(a1 & 0xffffffffLL);
        int s2 = (int)(a2 & 0xffffffffLL), s3 = (int)(a3 & 0xffffffffLL);
        float v0 = bf2f(yin[(size_t)s0 * FOUT + lane]);
        float v1 = bf2f(yin[(size_t)s1 * FOUT + lane]);
        float v2 = bf2f(yin[(size_t)s2 * FOUT + lane]);
        float v3 = bf2f(yin[(size_t)s3 * FOUT + lane]);
        acc += __int_as_float((int)(a0 >> 32)) * v0;
        acc += __int_as_float((int)(a1 >> 32)) * v1;
        acc += __int_as_float((int)(a2 >> 32)) * v2;
        acc += __int_as_float((int)(a3 >> 32)) * v3;
    }
    for (; j < end; ++j) {
        long long a = cw[j];
        int s = (int)(a & 0xffffffffLL);
        acc += __int_as_float((int)(a >> 32)) * bf2f(yin[(size_t)s * FOUT + lane]);
    }
    if (mode == 0) {
        yout_bf[(size_t)wid * FOUT + lane] = f2bf(acc);
    } else {
        yout_f[(size_t)wid * FOUT + lane] = acc + bias[lane];
    }
}

// ---- launch ---------------------------------------------------------------

extern "C" void kernel_launch(void* const* d_in, const int* in_sizes, int n_in,
                              void* d_out, int out_size, void* d_ws, size_t ws_size,
                              hipStream_t stream) {
    const float* x  = (const float*)d_in[0];
    const int*   ei = (const int*)d_in[1];
    const float* W  = (const float*)d_in[2];
    const float* b  = (const float*)d_in[3];
    float* out = (float*)d_out;

    int n = in_sizes[0] / FIN;   // 100000
    int e = in_sizes[1] / 2;     // 1600000
    int NB   = (n + 255) / 256;          // 391 (<= 1024 for scan2)
    int NBUK = (n + 127) >> BSH;         // 782 buckets

    char* w = (char*)d_ws;
    long long* cw  = (long long*)w; w += (size_t)e * sizeof(long long);      // 12.8 MB
    int*   bbuf   = (int*)w;   w += (size_t)NBUK * NGRP * CAP * sizeof(int); // 12.8 MB
    ushort_t* y0b = (ushort_t*)w; w += (size_t)n * FOUT * sizeof(ushort_t);  // 12.8 MB
    ushort_t* y1b = (ushort_t*)w; w += (size_t)n * FOUT * sizeof(ushort_t);  // 12.8 MB
    int*   bcur   = (int*)w;   w += (size_t)NBUK * NGRP * sizeof(int);
    int*   cnt    = (int*)w;   w += (size_t)n * sizeof(int);
    int*   rowptr = (int*)w;   w += (size_t)(n + 1) * sizeof(int);
    int*   excl   = (int*)w;   w += (size_t)n * sizeof(int);
    int*   bsum   = (int*)w;   w += (size_t)NB * sizeof(int);
    float* dinv   = (float*)w; w += (size_t)n * sizeof(float);

    int eb = (e + 255) / 256;

    (void)hipMemsetAsync(bcur, 0, (size_t)NBUK * NGRP * sizeof(int), stream);
    p1_bucket_kernel<<<eb, 256, 0, stream>>>(ei, bcur, bbuf, e);
    p2a_count_kernel<<<NBUK, 256, 0, stream>>>(bcur, bbuf, cnt, n);
    scan1_kernel<<<NB, 256, 0, stream>>>(cnt, excl, bsum, n);
    scan2_kernel<<<1, 1024, 0, stream>>>(bsum, NB);
    scan3_kernel<<<NB, 256, 0, stream>>>(cnt, excl, bsum, rowptr, dinv, n, e);
    p2b_place_kernel<<<NBUK, 256, 0, stream>>>(bcur, bbuf, rowptr, dinv, cw, n);

    xw_kernel<<<(n + BN - 1) / BN, 256, 0, stream>>>(x, W, y0b, n);
    prop_kernel<<<(n + 3) / 4, 256, 0, stream>>>(y0b, rowptr, cw, dinv, nullptr, y1b, nullptr, n, 0);
    prop_kernel<<<(n + 3) / 4, 256, 0, stream>>>(y1b, rowptr, cw, dinv, b, nullptr, out, n, 1);
}

// Round 8
// 287.156 us; speedup vs baseline: 1.3833x; 1.1591x over previous
//
#include <hip/hip_runtime.h>

// SGConv: out = A_norm^2 (x @ W^T) + b, A_norm = D^-1/2 (A+I) D^-1/2.
// Linear first (128->64), then 2 hops in 64-dim, bf16 storage / fp32 accum.
// CSR build: block-local counting sort in LDS with exact run claims and
// coalesced copy-out. R7 lesson: random 4B stores cost a 32B granule each
// (no L2 merge) and 1.6M contended global atomics are the true p1 bound —
// so: 16x fewer atomics (per-block-per-bucket claims) + wave-coalesced writes.

#define FIN 128
#define FOUT 64
#define BN 128
#define KC 64

#define NBUK 196          // buckets of 512 nodes (node >> 9)
#define BSH  9
#define NGRP 8            // claim-counter groups (blockIdx & 7), contention only
#define NSEG (NBUK * NGRP)
#define CAP  2048         // per-segment capacity (mean 1020, sigma ~31)
#define SEGSH 11          // CAP = 1 << 11
#define EPB_MAX 3328      // max edges per p1 block (actual 3125)
#define TILE_CAP 4608     // p2b half-bucket tile (mean 4096, sigma ~64)

typedef unsigned short ushort_t;
typedef unsigned int uint_t;

__device__ __forceinline__ ushort_t f2bf(float f) {           // RNE
    uint_t u = __float_as_uint(f);
    return (ushort_t)((u + 0x7fffu + ((u >> 16) & 1u)) >> 16);
}
__device__ __forceinline__ float bf2f(ushort_t v) {
    return __uint_as_float(((uint_t)v) << 16);
}

// ---- p1: block-local counting sort ---------------------------------------
// Per block: stage ~3125 edges in LDS, histogram 196 buckets, scan, claim
// exact per-bucket runs (1 global atomic each), sort into LDS, stream out
// coalesced. Entry = (dst&511)<<17 | src  (src < 2^17).

__global__ __launch_bounds__(512) void p1_sort_kernel(const int* __restrict__ ei,
                                                      int* __restrict__ bcur,
                                                      int* __restrict__ bbuf,
                                                      int e, int epb) {
    __shared__ int entryA[EPB_MAX];
    __shared__ int sortedC[EPB_MAX];
    __shared__ unsigned char bktA[EPB_MAX];
    __shared__ unsigned char bktS[EPB_MAX];
    __shared__ int hist[NBUK];
    __shared__ int stmp[256];
    __shared__ int loff[256];
    __shared__ int cur[NBUK];
    __shared__ int gbase[NBUK];

    const int tid = threadIdx.x;
    const int grp = blockIdx.x & (NGRP - 1);
    const int base = blockIdx.x * epb;
    int m = e - base; if (m > epb) m = epb; if (m < 0) m = 0;

    for (int i = tid; i < NBUK; i += 512) { hist[i] = 0; cur[i] = 0; }
    __syncthreads();

    // stage + histogram
    for (int i = tid; i < m; i += 512) {
        int s = ei[base + i];
        int d = ei[e + base + i];
        int b = d >> BSH;
        entryA[i] = ((d & 511) << 17) | s;
        bktA[i]   = (unsigned char)b;
        atomicAdd(&hist[b], 1);
    }
    __syncthreads();

    // exclusive scan of hist (256-thread Hillis-Steele; NBUK <= 256)
    int v = 0;
    if (tid < 256) { v = (tid < NBUK) ? hist[tid] : 0; stmp[tid] = v; }
    __syncthreads();
    for (int off = 1; off < 256; off <<= 1) {
        int add = 0;
        if (tid < 256 && tid >= off) add = stmp[tid - off];
        __syncthreads();
        if (tid < 256) stmp[tid] += add;
        __syncthreads();
    }
    if (tid < 256) loff[tid] = stmp[tid] - v;
    // claim global runs (exact sizes, 1 atomic per bucket per block)
    if (tid < NBUK) gbase[tid] = atomicAdd(&bcur[(tid << 3) | grp], hist[tid]);
    __syncthreads();

    // sort into LDS
    for (int i = tid; i < m; i += 512) {
        int b = bktA[i];
        int r = atomicAdd(&cur[b], 1);
        int p = loff[b] + r;
        sortedC[p] = entryA[i];
        bktS[p]    = (unsigned char)b;
    }
    __syncthreads();

    // coalesced copy-out: consecutive i -> consecutive global addresses
    for (int i = tid; i < m; i += 512) {
        int b   = bktS[i];
        int idx = gbase[b] + (i - loff[b]);
        if (idx < CAP)
            bbuf[(((b << 3) | grp) << SEGSH) + idx] = sortedC[i];
    }
}

// ---- p2a: per-bucket histogram -> cnt (coalesced) -------------------------

__global__ void p2a_count_kernel(const int* __restrict__ bcur, const int* __restrict__ bbuf,
                                 int* __restrict__ cnt, int n) {
    __shared__ int lc[512];
    int b = blockIdx.x, tid = threadIdx.x;
    lc[tid] = 0; lc[tid + 256] = 0;
    __syncthreads();
    for (int g = 0; g < NGRP; ++g) {
        int seg = (b << 3) | g;
        int mc = bcur[seg]; if (mc > CAP) mc = CAP;
        const int* p = bbuf + ((size_t)seg << SEGSH);
        for (int i = tid; i < mc; i += 256)
            atomicAdd(&lc[(p[i] >> 17) & 511], 1);
    }
    __syncthreads();
    int node0 = (b << BSH) + tid;
    if (node0 < n) cnt[node0] = lc[tid];
    if (node0 + 256 < n) cnt[node0 + 256] = lc[tid + 256];
}

// ---- scans ----------------------------------------------------------------

__global__ void scan1_kernel(const int* __restrict__ cnt, int* __restrict__ excl,
                             int* __restrict__ bsum, int n) {
    __shared__ int tmp[256];
    int t = threadIdx.x;
    int idx = blockIdx.x * 256 + t;
    int v = (idx < n) ? cnt[idx] : 0;
    tmp[t] = v;
    __syncthreads();
    for (int off = 1; off < 256; off <<= 1) {
        int add = (t >= off) ? tmp[t - off] : 0;
        __syncthreads();
        tmp[t] += add;
        __syncthreads();
    }
    if (idx < n) excl[idx] = tmp[t] - v;
    if (t == 255) bsum[blockIdx.x] = tmp[255];
}

__global__ void scan2_kernel(int* __restrict__ bsum, int nb) {
    __shared__ int tmp[1024];
    int t = threadIdx.x;
    int v = (t < nb) ? bsum[t] : 0;
    tmp[t] = v;
    __syncthreads();
    for (int off = 1; off < 1024; off <<= 1) {
        int add = (t >= off) ? tmp[t - off] : 0;
        __syncthreads();
        tmp[t] += add;
        __syncthreads();
    }
    if (t < nb) bsum[t] = tmp[t] - v;
}

__global__ void scan3_kernel(const int* __restrict__ cnt, const int* __restrict__ excl,
                             const int* __restrict__ bsum, int* __restrict__ rowptr,
                             float* __restrict__ dinv, int n, int e) {
    int idx = blockIdx.x * blockDim.x + threadIdx.x;
    if (idx < n) {
        rowptr[idx] = excl[idx] + bsum[idx >> 8];
        dinv[idx]   = rsqrtf((float)(cnt[idx] + 1));
    }
    if (idx == 0) rowptr[n] = e;
}

// ---- p2b: build sorted cw tile in LDS, stream out dense -------------------
// One block per 256-node half-bucket; reads the parent bucket's 8 segments,
// keeps its half, places {src,w} via LDS cursors, coalesced b64 copy-out.

__global__ void p2b_place_kernel(const int* __restrict__ bcur, const int* __restrict__ bbuf,
                                 const int* __restrict__ rowptr, const float* __restrict__ dinv,
                                 long long* __restrict__ cw, int n) {
    __shared__ int lcur[256];
    __shared__ float ldin[256];
    __shared__ long long tile[TILE_CAP];
    int hb = blockIdx.x, tid = threadIdx.x;
    int b  = hb >> 1;
    int half = hb & 1;
    int nodeBase = hb << 8;

    int nb0 = nodeBase < n ? nodeBase : n;
    int nb1 = (nodeBase + 256) < n ? (nodeBase + 256) : n;
    int tbase = rowptr[nb0];
    int tsize = rowptr[nb1] - tbase;
    if (tsize > TILE_CAP) tsize = TILE_CAP;

    int node = nodeBase + tid;
    lcur[tid] = (node < n) ? (rowptr[node] - tbase) : TILE_CAP;
    ldin[tid] = (node < n) ? dinv[node] : 0.f;
    __syncthreads();

    for (int g = 0; g < NGRP; ++g) {
        int seg = (b << 3) | g;
        int mc = bcur[seg]; if (mc > CAP) mc = CAP;
        const int* p = bbuf + ((size_t)seg << SEGSH);
        for (int i = tid; i < mc; i += 256) {
            int v  = p[i];
            int dl = (v >> 17) & 511;
            if ((dl >> 8) == half) {
                int dl2 = dl & 255;
                int s   = v & 0x1FFFF;
                int pos = atomicAdd(&lcur[dl2], 1);
                if (pos < TILE_CAP) {
                    float w = dinv[s] * ldin[dl2];
                    unsigned long long pk = (unsigned long long)(unsigned int)s |
                        ((unsigned long long)(unsigned int)__float_as_int(w) << 32);
                    tile[pos] = (long long)pk;
                }
            }
        }
    }
    __syncthreads();
    for (int i = tid; i < tsize; i += 256)
        cw[tbase + i] = tile[i];
}

// ---- y0 = x @ W^T : register-tiled SGEMM, bf16 output ---------------------

__global__ __launch_bounds__(256) void xw_kernel(const float* __restrict__ x,
                                                 const float* __restrict__ W,
                                                 ushort_t* __restrict__ y, int n) {
    __shared__ float4 xs4[KC][33];
    __shared__ float4 ws4[KC][17];
    float* xsf = (float*)xs4;
    float* wsf = (float*)ws4;

    const int tid   = threadIdx.x;
    const int node0 = blockIdx.x * BN;
    const int n8 = tid >> 4;
    const int o4 = tid & 15;

    float4 acc[8];
#pragma unroll
    for (int i = 0; i < 8; ++i) acc[i] = make_float4(0.f, 0.f, 0.f, 0.f);

    const int rx = tid >> 4;
    const int cx = tid & 15;

    for (int p = 0; p < FIN / KC; ++p) {
        __syncthreads();
#pragma unroll
        for (int i = 0; i < 8; ++i) {
            int r  = rx + 16 * i;
            int nd = node0 + r; if (nd > n - 1) nd = n - 1;
            float4 v = *(const float4*)(x + (size_t)nd * FIN + p * KC + 4 * cx);
            float* dst = xsf + (4 * cx) * 132 + r;
            dst[0] = v.x; dst[132] = v.y; dst[264] = v.z; dst[396] = v.w;
        }
#pragma unroll
        for (int i = 0; i < 4; ++i) {
            int o = rx + 16 * i;
            float4 v = *(const float4*)(W + (size_t)o * FIN + p * KC + 4 * cx);
            float* dst = wsf + (4 * cx) * 68 + o;
            dst[0] = v.x; dst[68] = v.y; dst[136] = v.z; dst[204] = v.w;
        }
        __syncthreads();
#pragma unroll 4
        for (int k = 0; k < KC; ++k) {
            float4 xa0 = xs4[k][2 * n8];
            float4 xa1 = xs4[k][2 * n8 + 1];
            float4 wb  = ws4[k][o4];
            float xe[8] = {xa0.x, xa0.y, xa0.z, xa0.w, xa1.x, xa1.y, xa1.z, xa1.w};
#pragma unroll
            for (int i = 0; i < 8; ++i) {
                acc[i].x += xe[i] * wb.x;
                acc[i].y += xe[i] * wb.y;
                acc[i].z += xe[i] * wb.z;
                acc[i].w += xe[i] * wb.w;
            }
        }
    }
#pragma unroll
    for (int i = 0; i < 8; ++i) {
        int nd = node0 + 8 * n8 + i;
        if (nd < n) {
            ushort4 o;
            o.x = f2bf(acc[i].x); o.y = f2bf(acc[i].y);
            o.z = f2bf(acc[i].z); o.w = f2bf(acc[i].w);
            *(ushort4*)(y + (size_t)nd * FOUT + 4 * o4) = o;
        }
    }
}

// ---- one propagation hop (bf16 in; bf16 or fp32+bias out) -----------------

__global__ void prop_kernel(const ushort_t* __restrict__ yin, const int* __restrict__ rowptr,
                            const long long* __restrict__ cw, const float* __restrict__ dinv,
                            const float* __restrict__ bias, ushort_t* __restrict__ yout_bf,
                            float* __restrict__ yout_f, int n, int mode) {
    int wid  = __builtin_amdgcn_readfirstlane((blockIdx.x * blockDim.x + threadIdx.x) >> 6);
    int lane = threadIdx.x & 63;
    if (wid >= n) return;
    float di  = dinv[wid];
    float acc = di * di * bf2f(yin[(size_t)wid * FOUT + lane]);
    int j = rowptr[wid], end = rowptr[wid + 1];
    for (; j + 3 < end; j += 4) {
        long long a0 = cw[j], a1 = cw[j + 1], a2 = cw[j + 2], a3 = cw[j + 3];
        int s0 = (int)(a0 & 0xffffffffLL), s1 = (int)(a1 & 0xffffffffLL);
        int s2 = (int)(a2 & 0xffffffffLL), s3 = (int)(a3 & 0xffffffffLL);
        float v0 = bf2f(yin[(size_t)s0 * FOUT + lane]);
        float v1 = bf2f(yin[(size_t)s1 * FOUT + lane]);
        float v2 = bf2f(yin[(size_t)s2 * FOUT + lane]);
        float v3 = bf2f(yin[(size_t)s3 * FOUT + lane]);
        acc += __int_as_float((int)(a0 >> 32)) * v0;
        acc += __int_as_float((int)(a1 >> 32)) * v1;
        acc += __int_as_float((int)(a2 >> 32)) * v2;
        acc += __int_as_float((int)(a3 >> 32)) * v3;
    }
    for (; j < end; ++j) {
        long long a = cw[j];
        int s = (int)(a & 0xffffffffLL);
        acc += __int_as_float((int)(a >> 32)) * bf2f(yin[(size_t)s * FOUT + lane]);
    }
    if (mode == 0) {
        yout_bf[(size_t)wid * FOUT + lane] = f2bf(acc);
    } else {
        yout_f[(size_t)wid * FOUT + lane] = acc + bias[lane];
    }
}

// ---- launch ---------------------------------------------------------------

extern "C" void kernel_launch(void* const* d_in, const int* in_sizes, int n_in,
                              void* d_out, int out_size, void* d_ws, size_t ws_size,
                              hipStream_t stream) {
    const float* x  = (const float*)d_in[0];
    const int*   ei = (const int*)d_in[1];
    const float* W  = (const float*)d_in[2];
    const float* b  = (const float*)d_in[3];
    float* out = (float*)d_out;

    int n = in_sizes[0] / FIN;   // 100000
    int e = in_sizes[1] / 2;     // 1600000
    int NB = (n + 255) / 256;    // 391 (<= 1024 for scan2)

    // p1 grid: ~3125 edges per block
    int P1B = (e + 3124) / 3125;             // 512
    int epb = (e + P1B - 1) / P1B;           // 3125 (must be <= EPB_MAX)

    char* w = (char*)d_ws;
    long long* cw  = (long long*)w; w += (size_t)e * sizeof(long long);      // 12.8 MB
    int*   bbuf   = (int*)w;   w += (size_t)NSEG * CAP * sizeof(int);        // 12.85 MB
    ushort_t* y0b = (ushort_t*)w; w += (size_t)n * FOUT * sizeof(ushort_t);  // 12.8 MB
    ushort_t* y1b = (ushort_t*)w; w += (size_t)n * FOUT * sizeof(ushort_t);  // 12.8 MB
    int*   bcur   = (int*)w;   w += (size_t)NSEG * sizeof(int);
    int*   cnt    = (int*)w;   w += (size_t)n * sizeof(int);
    int*   rowptr = (int*)w;   w += (size_t)(n + 1) * sizeof(int);
    int*   excl   = (int*)w;   w += (size_t)n * sizeof(int);
    int*   bsum   = (int*)w;   w += (size_t)NB * sizeof(int);
    float* dinv   = (float*)w; w += (size_t)n * sizeof(float);

    (void)hipMemsetAsync(bcur, 0, (size_t)NSEG * sizeof(int), stream);
    p1_sort_kernel<<<P1B, 512, 0, stream>>>(ei, bcur, bbuf, e, epb);
    p2a_count_kernel<<<NBUK, 256, 0, stream>>>(bcur, bbuf, cnt, n);
    scan1_kernel<<<NB, 256, 0, stream>>>(cnt, excl, bsum, n);
    scan2_kernel<<<1, 1024, 0, stream>>>(bsum, NB);
    scan3_kernel<<<NB, 256, 0, stream>>>(cnt, excl, bsum, rowptr, dinv, n, e);
    p2b_place_kernel<<<NBUK * 2, 256, 0, stream>>>(bcur, bbuf, rowptr, dinv, cw, n);

    xw_kernel<<<(n + BN - 1) / BN, 256, 0, stream>>>(x, W, y0b, n);
    prop_kernel<<<(n + 3) / 4, 256, 0, stream>>>(y0b, rowptr, cw, dinv, nullptr, y1b, nullptr, n, 0);
    prop_kernel<<<(n + 3) / 4, 256, 0, stream>>>(y1b, rowptr, cw, dinv, b, nullptr, out, n, 1);
}

// Round 9
// 276.566 us; speedup vs baseline: 1.4362x; 1.0383x over previous
//
#include <hip/hip_runtime.h>

// SGConv: out = A_norm^2 (x @ W^T) + b, A_norm = D^-1/2 (A+I) D^-1/2.
// Key algebra: store y-hat = dinv (.) h (bf16). Then a hop is
//   h'_d = dinv_d * (sum_{s in N(d)} yhat_s + yhat_d)
// -> NO per-edge weights; CSR payload is a bare 4B src index.

#define FIN 128
#define FOUT 64
#define BN 128
#define KC 64

#define NBUK 196          // buckets of 512 nodes (node >> 9)
#define BSH  9
#define NGRP 8
#define NSEG (NBUK * NGRP)
#define CAP  2048
#define SEGSH 11
#define EPB_MAX 3328
#define TILE_CAP 4608     // p2b half-bucket tile (mean 4096, sigma ~64)

typedef unsigned short ushort_t;
typedef unsigned int uint_t;

__device__ __forceinline__ ushort_t f2bf(float f) {           // RNE
    uint_t u = __float_as_uint(f);
    return (ushort_t)((u + 0x7fffu + ((u >> 16) & 1u)) >> 16);
}
__device__ __forceinline__ float bf2f(ushort_t v) {
    return __uint_as_float(((uint_t)v) << 16);
}

// ---- p1: block-local counting sort into (bucket, grp) segments ------------

__global__ __launch_bounds__(512) void p1_sort_kernel(const int* __restrict__ ei,
                                                      int* __restrict__ bcur,
                                                      int* __restrict__ bbuf,
                                                      int e, int epb) {
    __shared__ int entryA[EPB_MAX];
    __shared__ int sortedC[EPB_MAX];
    __shared__ unsigned char bktA[EPB_MAX];
    __shared__ unsigned char bktS[EPB_MAX];
    __shared__ int hist[NBUK];
    __shared__ int stmp[256];
    __shared__ int loff[256];
    __shared__ int cur[NBUK];
    __shared__ int gbase[NBUK];

    const int tid = threadIdx.x;
    const int grp = blockIdx.x & (NGRP - 1);
    const int base = blockIdx.x * epb;
    int m = e - base; if (m > epb) m = epb; if (m < 0) m = 0;

    for (int i = tid; i < NBUK; i += 512) { hist[i] = 0; cur[i] = 0; }
    __syncthreads();

    for (int i = tid; i < m; i += 512) {
        int s = ei[base + i];
        int d = ei[e + base + i];
        int b = d >> BSH;
        entryA[i] = ((d & 511) << 17) | s;
        bktA[i]   = (unsigned char)b;
        atomicAdd(&hist[b], 1);
    }
    __syncthreads();

    int v = 0;
    if (tid < 256) { v = (tid < NBUK) ? hist[tid] : 0; stmp[tid] = v; }
    __syncthreads();
    for (int off = 1; off < 256; off <<= 1) {
        int add = 0;
        if (tid < 256 && tid >= off) add = stmp[tid - off];
        __syncthreads();
        if (tid < 256) stmp[tid] += add;
        __syncthreads();
    }
    if (tid < 256) loff[tid] = stmp[tid] - v;
    if (tid < NBUK) gbase[tid] = atomicAdd(&bcur[(tid << 3) | grp], hist[tid]);
    __syncthreads();

    for (int i = tid; i < m; i += 512) {
        int b = bktA[i];
        int r = atomicAdd(&cur[b], 1);
        int p = loff[b] + r;
        sortedC[p] = entryA[i];
        bktS[p]    = (unsigned char)b;
    }
    __syncthreads();

    for (int i = tid; i < m; i += 512) {
        int b   = bktS[i];
        int idx = gbase[b] + (i - loff[b]);
        if (idx < CAP)
            bbuf[(((b << 3) | grp) << SEGSH) + idx] = sortedC[i];
    }
}

// ---- p2a: per-bucket histogram -> cnt + dinv (coalesced) ------------------

__global__ void p2a_count_kernel(const int* __restrict__ bcur, const int* __restrict__ bbuf,
                                 int* __restrict__ cnt, float* __restrict__ dinv, int n) {
    __shared__ int lc[512];
    int b = blockIdx.x, tid = threadIdx.x;
    lc[tid] = 0; lc[tid + 256] = 0;
    __syncthreads();
    for (int g = 0; g < NGRP; ++g) {
        int seg = (b << 3) | g;
        int mc = bcur[seg]; if (mc > CAP) mc = CAP;
        const int* p = bbuf + ((size_t)seg << SEGSH);
        for (int i = tid; i < mc; i += 256)
            atomicAdd(&lc[(p[i] >> 17) & 511], 1);
    }
    __syncthreads();
#pragma unroll
    for (int h = 0; h < 2; ++h) {
        int node = (b << BSH) + tid + 256 * h;
        if (node < n) {
            int c = lc[tid + 256 * h];
            cnt[node]  = c;
            dinv[node] = rsqrtf((float)(c + 1));
        }
    }
}

// ---- scans ----------------------------------------------------------------

__global__ void scan1_kernel(const int* __restrict__ cnt, int* __restrict__ excl,
                             int* __restrict__ bsum, int n) {
    __shared__ int tmp[256];
    int t = threadIdx.x;
    int idx = blockIdx.x * 256 + t;
    int v = (idx < n) ? cnt[idx] : 0;
    tmp[t] = v;
    __syncthreads();
    for (int off = 1; off < 256; off <<= 1) {
        int add = (t >= off) ? tmp[t - off] : 0;
        __syncthreads();
        tmp[t] += add;
        __syncthreads();
    }
    if (idx < n) excl[idx] = tmp[t] - v;
    if (t == 255) bsum[blockIdx.x] = tmp[255];
}

__global__ void scan2_kernel(int* __restrict__ bsum, int nb) {
    __shared__ int tmp[1024];
    int t = threadIdx.x;
    int v = (t < nb) ? bsum[t] : 0;
    tmp[t] = v;
    __syncthreads();
    for (int off = 1; off < 1024; off <<= 1) {
        int add = (t >= off) ? tmp[t - off] : 0;
        __syncthreads();
        tmp[t] += add;
        __syncthreads();
    }
    if (t < nb) bsum[t] = tmp[t] - v;
}

__global__ void scan3_kernel(const int* __restrict__ excl, const int* __restrict__ bsum,
                             int* __restrict__ rowptr, int n, int e) {
    int idx = blockIdx.x * blockDim.x + threadIdx.x;
    if (idx < n) rowptr[idx] = excl[idx] + bsum[idx >> 8];
    if (idx == 0) rowptr[n] = e;
}

// ---- p2b: build sorted col tile in LDS, stream out dense ------------------

__global__ void p2b_place_kernel(const int* __restrict__ bcur, const int* __restrict__ bbuf,
                                 const int* __restrict__ rowptr, int* __restrict__ col, int n) {
    __shared__ int lcur[256];
    __shared__ int tile[TILE_CAP];
    int hb = blockIdx.x, tid = threadIdx.x;
    int b  = hb >> 1;
    int half = hb & 1;
    int nodeBase = hb << 8;

    int nb0 = nodeBase < n ? nodeBase : n;
    int nb1 = (nodeBase + 256) < n ? (nodeBase + 256) : n;
    int tbase = rowptr[nb0];
    int tsize = rowptr[nb1] - tbase;
    if (tsize > TILE_CAP) tsize = TILE_CAP;

    int node = nodeBase + tid;
    lcur[tid] = (node < n) ? (rowptr[node] - tbase) : TILE_CAP;
    __syncthreads();

    for (int g = 0; g < NGRP; ++g) {
        int seg = (b << 3) | g;
        int mc = bcur[seg]; if (mc > CAP) mc = CAP;
        const int* p = bbuf + ((size_t)seg << SEGSH);
        for (int i = tid; i < mc; i += 256) {
            int v  = p[i];
            int dl = (v >> 17) & 511;
            if ((dl >> 8) == half) {
                int pos = atomicAdd(&lcur[dl & 255], 1);
                if (pos < TILE_CAP) tile[pos] = v & 0x1FFFF;   // src
            }
        }
    }
    __syncthreads();
    for (int i = tid; i < tsize; i += 256)
        col[tbase + i] = tile[i];
}

// ---- y0hat = dinv (.) (x @ W^T) : register-tiled SGEMM, bf16 out ----------

__global__ __launch_bounds__(256) void xw_kernel(const float* __restrict__ x,
                                                 const float* __restrict__ W,
                                                 const float* __restrict__ dinv,
                                                 ushort_t* __restrict__ y, int n) {
    __shared__ float4 xs4[KC][33];
    __shared__ float4 ws4[KC][17];
    float* xsf = (float*)xs4;
    float* wsf = (float*)ws4;

    const int tid   = threadIdx.x;
    const int node0 = blockIdx.x * BN;
    const int n8 = tid >> 4;
    const int o4 = tid & 15;

    float4 acc[8];
#pragma unroll
    for (int i = 0; i < 8; ++i) acc[i] = make_float4(0.f, 0.f, 0.f, 0.f);

    const int rx = tid >> 4;
    const int cx = tid & 15;

    for (int p = 0; p < FIN / KC; ++p) {
        __syncthreads();
#pragma unroll
        for (int i = 0; i < 8; ++i) {
            int r  = rx + 16 * i;
            int nd = node0 + r; if (nd > n - 1) nd = n - 1;
            float4 v = *(const float4*)(x + (size_t)nd * FIN + p * KC + 4 * cx);
            float* dst = xsf + (4 * cx) * 132 + r;
            dst[0] = v.x; dst[132] = v.y; dst[264] = v.z; dst[396] = v.w;
        }
#pragma unroll
        for (int i = 0; i < 4; ++i) {
            int o = rx + 16 * i;
            float4 v = *(const float4*)(W + (size_t)o * FIN + p * KC + 4 * cx);
            float* dst = wsf + (4 * cx) * 68 + o;
            dst[0] = v.x; dst[68] = v.y; dst[136] = v.z; dst[204] = v.w;
        }
        __syncthreads();
#pragma unroll 4
        for (int k = 0; k < KC; ++k) {
            float4 xa0 = xs4[k][2 * n8];
            float4 xa1 = xs4[k][2 * n8 + 1];
            float4 wb  = ws4[k][o4];
            float xe[8] = {xa0.x, xa0.y, xa0.z, xa0.w, xa1.x, xa1.y, xa1.z, xa1.w};
#pragma unroll
            for (int i = 0; i < 8; ++i) {
                acc[i].x += xe[i] * wb.x;
                acc[i].y += xe[i] * wb.y;
                acc[i].z += xe[i] * wb.z;
                acc[i].w += xe[i] * wb.w;
            }
        }
    }
#pragma unroll
    for (int i = 0; i < 8; ++i) {
        int nd = node0 + 8 * n8 + i;
        if (nd < n) {
            float di = dinv[nd];
            ushort4 o;
            o.x = f2bf(di * acc[i].x); o.y = f2bf(di * acc[i].y);
            o.z = f2bf(di * acc[i].z); o.w = f2bf(di * acc[i].w);
            *(ushort4*)(y + (size_t)nd * FOUT + 4 * o4) = o;
        }
    }
}

// ---- one propagation hop: acc = sum yhat[src] + yhat[self] ----------------
// mode 0: yout_bf = f2bf(dinv^2 * acc)   (stores yhat for next hop)
// mode 1: yout_f  = dinv * acc + bias    (final output)

__global__ __launch_bounds__(512) void prop_kernel(const ushort_t* __restrict__ yin,
                            const int* __restrict__ rowptr, const int* __restrict__ col,
                            const float* __restrict__ dinv, const float* __restrict__ bias,
                            ushort_t* __restrict__ yout_bf, float* __restrict__ yout_f,
                            int n, int mode) {
    int wid  = __builtin_amdgcn_readfirstlane((blockIdx.x * blockDim.x + threadIdx.x) >> 6);
    int lane = threadIdx.x & 63;
    if (wid >= n) return;
    float acc = bf2f(yin[(size_t)wid * FOUT + lane]);   // self loop
    int j = rowptr[wid], end = rowptr[wid + 1];
    for (; j + 7 < end; j += 8) {
        int s0 = col[j],     s1 = col[j + 1], s2 = col[j + 2], s3 = col[j + 3];
        int s4 = col[j + 4], s5 = col[j + 5], s6 = col[j + 6], s7 = col[j + 7];
        float v0 = bf2f(yin[(size_t)s0 * FOUT + lane]);
        float v1 = bf2f(yin[(size_t)s1 * FOUT + lane]);
        float v2 = bf2f(yin[(size_t)s2 * FOUT + lane]);
        float v3 = bf2f(yin[(size_t)s3 * FOUT + lane]);
        float v4 = bf2f(yin[(size_t)s4 * FOUT + lane]);
        float v5 = bf2f(yin[(size_t)s5 * FOUT + lane]);
        float v6 = bf2f(yin[(size_t)s6 * FOUT + lane]);
        float v7 = bf2f(yin[(size_t)s7 * FOUT + lane]);
        acc += ((v0 + v1) + (v2 + v3)) + ((v4 + v5) + (v6 + v7));
    }
    for (; j < end; ++j)
        acc += bf2f(yin[(size_t)col[j] * FOUT + lane]);
    float di = dinv[wid];
    if (mode == 0) {
        yout_bf[(size_t)wid * FOUT + lane] = f2bf(di * di * acc);
    } else {
        yout_f[(size_t)wid * FOUT + lane] = di * acc + bias[lane];
    }
}

// ---- launch ---------------------------------------------------------------

extern "C" void kernel_launch(void* const* d_in, const int* in_sizes, int n_in,
                              void* d_out, int out_size, void* d_ws, size_t ws_size,
                              hipStream_t stream) {
    const float* x  = (const float*)d_in[0];
    const int*   ei = (const int*)d_in[1];
    const float* W  = (const float*)d_in[2];
    const float* b  = (const float*)d_in[3];
    float* out = (float*)d_out;

    int n = in_sizes[0] / FIN;   // 100000
    int e = in_sizes[1] / 2;     // 1600000
    int NB = (n + 255) / 256;    // 391

    int P1B = (e + 3124) / 3125;             // 512
    int epb = (e + P1B - 1) / P1B;           // 3125 <= EPB_MAX

    char* w = (char*)d_ws;
    int*   bbuf   = (int*)w;   w += (size_t)NSEG * CAP * sizeof(int);        // 12.85 MB
    int*   col    = (int*)w;   w += (size_t)e * sizeof(int);                 // 6.4 MB
    ushort_t* y0b = (ushort_t*)w; w += (size_t)n * FOUT * sizeof(ushort_t);  // 12.8 MB
    ushort_t* y1b = (ushort_t*)w; w += (size_t)n * FOUT * sizeof(ushort_t);  // 12.8 MB
    int*   bcur   = (int*)w;   w += (size_t)NSEG * sizeof(int);
    int*   cnt    = (int*)w;   w += (size_t)n * sizeof(int);
    int*   rowptr = (int*)w;   w += (size_t)(n + 1) * sizeof(int);
    int*   excl   = (int*)w;   w += (size_t)n * sizeof(int);
    int*   bsum   = (int*)w;   w += (size_t)NB * sizeof(int);
    float* dinv   = (float*)w; w += (size_t)n * sizeof(float);

    (void)hipMemsetAsync(bcur, 0, (size_t)NSEG * sizeof(int), stream);
    p1_sort_kernel<<<P1B, 512, 0, stream>>>(ei, bcur, bbuf, e, epb);
    p2a_count_kernel<<<NBUK, 256, 0, stream>>>(bcur, bbuf, cnt, dinv, n);
    scan1_kernel<<<NB, 256, 0, stream>>>(cnt, excl, bsum, n);
    scan2_kernel<<<1, 1024, 0, stream>>>(bsum, NB);
    scan3_kernel<<<NB, 256, 0, stream>>>(excl, bsum, rowptr, n, e);
    p2b_place_kernel<<<NBUK * 2, 256, 0, stream>>>(bcur, bbuf, rowptr, col, n);

    xw_kernel<<<(n + BN - 1) / BN, 256, 0, stream>>>(x, W, dinv, y0b, n);
    prop_kernel<<<(n + 7) / 8, 512, 0, stream>>>(y0b, rowptr, col, dinv, nullptr, y1b, nullptr, n, 0);
    prop_kernel<<<(n + 7) / 8, 512, 0, stream>>>(y1b, rowptr, col, dinv, b, nullptr, out, n, 1);
}